// Round 5
// baseline (458.799 us; speedup 1.0000x reference)
//
#include <hip/hip_runtime.h>
#include <stdint.h>

#define H 32
#define HKV 8
#define D 128
#define SQ 1024
#define CTX 3072
#define SKV 4096
#define FP8_MAX_C 448.0f
#define EPS_C 1e-8f

typedef __attribute__((ext_vector_type(4))) float f32x4;
typedef __attribute__((ext_vector_type(8))) __bf16 bf16x8;
typedef __attribute__((ext_vector_type(8))) unsigned short u16x8;
typedef __attribute__((ext_vector_type(4))) unsigned short u16x4;

__device__ __forceinline__ unsigned short f2bf(float x) {
  unsigned int u = __builtin_bit_cast(unsigned int, x);
  u += 0x7fffu + ((u >> 16) & 1u);
  return (unsigned short)(u >> 16);
}

__device__ __forceinline__ f32x4 mfma16(bf16x8 a, bf16x8 b, f32x4 c) {
  return __builtin_amdgcn_mfma_f32_16x16x32_bf16(a, b, c, 0, 0, 0);
}

// ---- scales stage 1: partial absmax -> atomicMax on float bits ----
__global__ void scales_part(const float* __restrict__ k,
                            const float* __restrict__ v,
                            unsigned int* __restrict__ smax) {
  const int b = blockIdx.x & 15;
  const int part = blockIdx.x >> 4;
  const float* src = (b < HKV) ? k : v;
  const int h = b & 7;
  const int tid = threadIdx.x;
  const int d0 = (tid & 31) * 4;
  float mx = 0.f;
  const int t1 = part * 128 + 128;
  for (int t = part * 128 + (tid >> 5); t < t1; t += 8) {
    float4 vv = *reinterpret_cast<const float4*>(src + (size_t)t * (HKV * D) + h * D + d0);
    mx = fmaxf(mx, fmaxf(fmaxf(fabsf(vv.x), fabsf(vv.y)),
                         fmaxf(fabsf(vv.z), fabsf(vv.w))));
  }
  __shared__ float red[256];
  red[tid] = mx;
  __syncthreads();
  for (int s = 128; s > 0; s >>= 1) {
    if (tid < s) red[tid] = fmaxf(red[tid], red[tid + s]);
    __syncthreads();
  }
  if (tid == 0) atomicMax(&smax[b], __float_as_uint(red[0]));
}

__global__ void scales_fin(const unsigned int* __restrict__ smax,
                           float* __restrict__ scales) {
  const int i = threadIdx.x;
  if (i < 16) scales[i] = fmaxf(__uint_as_float(smax[i]) / FP8_MAX_C, EPS_C);
}

// ---- prep k_comb[h][t][d] bf16 ----
__global__ void prep_k(const float* __restrict__ k,
                       const float* __restrict__ k_cache,
                       const int* __restrict__ cache_slots,
                       const float* __restrict__ scales,
                       unsigned short* __restrict__ k_comb) {
  const int tid = blockIdx.x * 256 + threadIdx.x;
  const int d8 = tid & 15;
  const int t = (tid >> 4) & (SKV - 1);
  const int h = tid >> 16;
  const int d0 = d8 * 8;
  const float* src;
  float mul;
  if (t < CTX) {
    int slot = cache_slots[t];
    src = k_cache + (size_t)slot * (HKV * D) + h * D + d0;
    mul = scales[h];
  } else {
    src = k + (size_t)(t - CTX) * (HKV * D) + h * D + d0;
    mul = 1.f;
  }
  float4 a = *reinterpret_cast<const float4*>(src);
  float4 bb = *reinterpret_cast<const float4*>(src + 4);
  u16x8 r;
  r[0] = f2bf(a.x * mul);  r[1] = f2bf(a.y * mul);
  r[2] = f2bf(a.z * mul);  r[3] = f2bf(a.w * mul);
  r[4] = f2bf(bb.x * mul); r[5] = f2bf(bb.y * mul);
  r[6] = f2bf(bb.z * mul); r[7] = f2bf(bb.w * mul);
  *reinterpret_cast<u16x8*>(k_comb + ((size_t)h * SKV + t) * D + d0) = r;
}

// ---- prep v_combT[h][d][t] bf16 ----
__global__ void prep_v(const float* __restrict__ v,
                       const float* __restrict__ v_cache,
                       const int* __restrict__ cache_slots,
                       const float* __restrict__ scales,
                       unsigned short* __restrict__ v_combT) {
  const int tid = blockIdx.x * 256 + threadIdx.x;
  const int d = tid & 127;
  const int t8 = (tid >> 7) & 511;
  const int h = tid >> 16;
  const int t0 = t8 * 8;
  const float sc = scales[8 + h];
  u16x8 r;
#pragma unroll
  for (int i = 0; i < 8; ++i) {
    int t = t0 + i;
    float val;
    if (t < CTX) {
      int slot = cache_slots[t];
      val = v_cache[(size_t)slot * (HKV * D) + h * D + d] * sc;
    } else {
      val = v[(size_t)(t - CTX) * (HKV * D) + h * D + d];
    }
    r[i] = f2bf(val);
  }
  *reinterpret_cast<u16x8*>(v_combT + ((size_t)h * D + d) * SKV + t0) = r;
}

#define LDBF(p) (*reinterpret_cast<const bf16x8*>(p))
#define Z4 ((f32x4){0.f, 0.f, 0.f, 0.f})

// sf stride = 16*D = 2048, ks stride = 32
#define LOADK(TB)                                                              \
  {                                                                            \
    const unsigned short* kp = kb + (size_t)((TB) + lo) * D + g * 8;           \
    k00 = LDBF(kp + 0);    k01 = LDBF(kp + 32);                                \
    k02 = LDBF(kp + 64);   k03 = LDBF(kp + 96);                                \
    k10 = LDBF(kp + 2048); k11 = LDBF(kp + 2080);                              \
    k12 = LDBF(kp + 2112); k13 = LDBF(kp + 2144);                              \
    k20 = LDBF(kp + 4096); k21 = LDBF(kp + 4128);                              \
    k22 = LDBF(kp + 4160); k23 = LDBF(kp + 4192);                              \
    k30 = LDBF(kp + 6144); k31 = LDBF(kp + 6176);                              \
    k32 = LDBF(kp + 6208); k33 = LDBF(kp + 6240);                              \
  }

// exp2 + pack one s-register (4 q-rows worth for this lane's 4 kv values)
#define PK(SREG, PKREG)                                                        \
  {                                                                            \
    float p0_ = __builtin_amdgcn_exp2f(SREG[0] - m);                           \
    float p1_ = __builtin_amdgcn_exp2f(SREG[1] - m);                           \
    float p2_ = __builtin_amdgcn_exp2f(SREG[2] - m);                           \
    float p3_ = __builtin_amdgcn_exp2f(SREG[3] - m);                           \
    rs += (p0_ + p1_) + (p2_ + p3_);                                           \
    PKREG[0] = f2bf(p0_); PKREG[1] = f2bf(p1_);                                \
    PKREG[2] = f2bf(p2_); PKREG[3] = f2bf(p3_);                                \
  }

// ---- flash attention: swapped QK^T, KVBLK=64, fully hand-unrolled ----
__launch_bounds__(256, 2)
__global__ void attn_kernel(const float* __restrict__ q,
                            const unsigned short* __restrict__ k_comb,
                            const unsigned short* __restrict__ v_combT,
                            float* __restrict__ out) {
  const int bid = blockIdx.x;
  const int hkv = bid & 7;   // XCD-aware: one kv-head per XCD
  const int qt = bid >> 3;   // 0..63
  const int wid = threadIdx.x >> 6;
  const int l = threadIdx.x & 63;
  const int lo = l & 15;
  const int g = l >> 4;
  const int hq = hkv * 4 + wid;
  const int qbase = qt * 16;
  const int nt32 = 97 + (qt >> 1);
  const int n64 = (nt32 + 1) >> 1;
  const bool odd = (nt32 & 1) != 0;

  // Q fragments (B-operand), pre-scaled by SCALE*log2(e)
  bf16x8 qf0, qf1, qf2, qf3;
  {
    const float qs = 0.088388347648318447f * 1.4426950408889634f;
    const float* qp = q + (size_t)(qbase + lo) * (H * D) + hq * D;
#define QLOAD(KS, DST)                                                         \
    {                                                                          \
      float4 a = *reinterpret_cast<const float4*>(qp + KS * 32 + g * 8);       \
      float4 b = *reinterpret_cast<const float4*>(qp + KS * 32 + g * 8 + 4);   \
      union { unsigned short u[8]; bf16x8 v; } f;                              \
      f.u[0] = f2bf(a.x * qs); f.u[1] = f2bf(a.y * qs);                        \
      f.u[2] = f2bf(a.z * qs); f.u[3] = f2bf(a.w * qs);                        \
      f.u[4] = f2bf(b.x * qs); f.u[5] = f2bf(b.y * qs);                        \
      f.u[6] = f2bf(b.z * qs); f.u[7] = f2bf(b.w * qs);                        \
      DST = f.v;                                                               \
    }
    QLOAD(0, qf0) QLOAD(1, qf1) QLOAD(2, qf2) QLOAD(3, qf3)
#undef QLOAD
  }

  f32x4 acc0 = Z4, acc1 = Z4, acc2 = Z4, acc3 = Z4;
  f32x4 acc4 = Z4, acc5 = Z4, acc6 = Z4, acc7 = Z4;
  float m = -1e30f;   // running row max (log2 units); row = lo
  float lsum = 0.f;   // per-lane partial denom

  __shared__ __align__(16) unsigned short p_lds[4][16][72];

  const unsigned short* kb = k_comb + (size_t)hkv * SKV * D;
  const unsigned short* vb = v_combT + (size_t)hkv * D * SKV;

  bf16x8 k00, k01, k02, k03, k10, k11, k12, k13;
  bf16x8 k20, k21, k22, k23, k30, k31, k32, k33;
  LOADK(0)

  for (int t = 0; t < n64; ++t) {
    const int tb = t * 64;

    // ---- issue V loads first (latency hides under QK) ----
    bf16x8 v0a, v0b, v1a, v1b, v2a, v2b, v3a, v3b;
    bf16x8 v4a, v4b, v5a, v5b, v6a, v6b, v7a, v7b;
    {
      const unsigned short* vp = vb + (size_t)lo * SKV + tb + g * 8;
      v0a = LDBF(vp + 0 * 65536);  v0b = LDBF(vp + 0 * 65536 + 32);
      v1a = LDBF(vp + 1 * 65536);  v1b = LDBF(vp + 1 * 65536 + 32);
      v2a = LDBF(vp + 2 * 65536);  v2b = LDBF(vp + 2 * 65536 + 32);
      v3a = LDBF(vp + 3 * 65536);  v3b = LDBF(vp + 3 * 65536 + 32);
      v4a = LDBF(vp + 4 * 65536);  v4b = LDBF(vp + 4 * 65536 + 32);
      v5a = LDBF(vp + 5 * 65536);  v5b = LDBF(vp + 5 * 65536 + 32);
      v6a = LDBF(vp + 6 * 65536);  v6b = LDBF(vp + 6 * 65536 + 32);
      v7a = LDBF(vp + 7 * 65536);  v7b = LDBF(vp + 7 * 65536 + 32);
    }

    // ---- QK^T swapped: s{sf} = S^T[kv rows][q cols] ----
    f32x4 s0 = Z4, s1 = Z4, s2 = Z4, s3 = Z4;
    s0 = mfma16(k00, qf0, s0); s0 = mfma16(k01, qf1, s0);
    s0 = mfma16(k02, qf2, s0); s0 = mfma16(k03, qf3, s0);
    s1 = mfma16(k10, qf0, s1); s1 = mfma16(k11, qf1, s1);
    s1 = mfma16(k12, qf2, s1); s1 = mfma16(k13, qf3, s1);
    s2 = mfma16(k20, qf0, s2); s2 = mfma16(k21, qf1, s2);
    s2 = mfma16(k22, qf2, s2); s2 = mfma16(k23, qf3, s2);
    s3 = mfma16(k30, qf0, s3); s3 = mfma16(k31, qf1, s3);
    s3 = mfma16(k32, qf2, s3); s3 = mfma16(k33, qf3, s3);

    // ---- prefetch next K tile in place (final-iter overreach is in-bounds
    //      scratch: lands in v_combT region) ----
    LOADK(tb + 64)

    // ---- mask invalid upper half of odd-count last tile ----
    if (odd && t == n64 - 1) {
      s2 = (f32x4){-1e30f, -1e30f, -1e30f, -1e30f};
      s3 = (f32x4){-1e30f, -1e30f, -1e30f, -1e30f};
    }

    // ---- lazy online softmax: no cross-lane ops in the common path ----
    float pmax = fmaxf(fmaxf(fmaxf(s0[0], s0[1]), fmaxf(s0[2], s0[3])),
                       fmaxf(fmaxf(s1[0], s1[1]), fmaxf(s1[2], s1[3])));
    pmax = fmaxf(pmax,
                 fmaxf(fmaxf(fmaxf(s2[0], s2[1]), fmaxf(s2[2], s2[3])),
                       fmaxf(fmaxf(s3[0], s3[1]), fmaxf(s3[2], s3[3]))));
    if (!__all(pmax - m <= 8.f)) {  // rescale path (rare)
      float rm = fmaxf(pmax, __shfl_xor(pmax, 16));
      rm = fmaxf(rm, __shfl_xor(rm, 32));
      float mn = fmaxf(m, rm);
      float scl = __builtin_amdgcn_exp2f(m - mn);
      lsum *= scl;
      acc0 *= scl; acc1 *= scl; acc2 *= scl; acc3 *= scl;
      acc4 *= scl; acc5 *= scl; acc6 *= scl; acc7 *= scl;
      m = mn;
    }

    float rs = 0.f;
    u16x4 pk0, pk1, pk2, pk3;
    PK(s0, pk0) PK(s1, pk1) PK(s2, pk2) PK(s3, pk3)
    lsum += rs;

    // ---- P transpose through per-wave LDS (no barrier) ----
    *reinterpret_cast<u16x4*>(&p_lds[wid][lo][0 * 16 + g * 4]) = pk0;
    *reinterpret_cast<u16x4*>(&p_lds[wid][lo][1 * 16 + g * 4]) = pk1;
    *reinterpret_cast<u16x4*>(&p_lds[wid][lo][2 * 16 + g * 4]) = pk2;
    *reinterpret_cast<u16x4*>(&p_lds[wid][lo][3 * 16 + g * 4]) = pk3;
    bf16x8 pf0 = LDBF(&p_lds[wid][lo][g * 8]);
    bf16x8 pf1 = LDBF(&p_lds[wid][lo][32 + g * 8]);

    // ---- PV ----
    acc0 = mfma16(pf0, v0a, acc0); acc0 = mfma16(pf1, v0b, acc0);
    acc1 = mfma16(pf0, v1a, acc1); acc1 = mfma16(pf1, v1b, acc1);
    acc2 = mfma16(pf0, v2a, acc2); acc2 = mfma16(pf1, v2b, acc2);
    acc3 = mfma16(pf0, v3a, acc3); acc3 = mfma16(pf1, v3b, acc3);
    acc4 = mfma16(pf0, v4a, acc4); acc4 = mfma16(pf1, v4b, acc4);
    acc5 = mfma16(pf0, v5a, acc5); acc5 = mfma16(pf1, v5b, acc5);
    acc6 = mfma16(pf0, v6a, acc6); acc6 = mfma16(pf1, v6b, acc6);
    acc7 = mfma16(pf0, v7a, acc7); acc7 = mfma16(pf1, v7b, acc7);
  }

  // ---- epilogue: reduce denom, broadcast to C-layout rows, store ----
  lsum += __shfl_xor(lsum, 16);
  lsum += __shfl_xor(lsum, 32);
#pragma unroll
  for (int r = 0; r < 4; ++r) {
    int src = (l & 48) | (g * 4 + r);
    float inv = 1.f / __shfl(lsum, src);
    float* op = out + (size_t)(qbase + g * 4 + r) * (H * D) + hq * D + lo;
    op[0 * 16] = acc0[r] * inv;
    op[1 * 16] = acc1[r] * inv;
    op[2 * 16] = acc2[r] * inv;
    op[3 * 16] = acc3[r] * inv;
    op[4 * 16] = acc4[r] * inv;
    op[5 * 16] = acc5[r] * inv;
    op[6 * 16] = acc6[r] * inv;
    op[7 * 16] = acc7[r] * inv;
  }
}

extern "C" void kernel_launch(void* const* d_in, const int* in_sizes, int n_in,
                              void* d_out, int out_size, void* d_ws, size_t ws_size,
                              hipStream_t stream) {
  (void)in_sizes; (void)n_in; (void)out_size; (void)ws_size;
  const float* q = (const float*)d_in[0];
  const float* k = (const float*)d_in[1];
  const float* v = (const float*)d_in[2];
  const float* k_cache = (const float*)d_in[3];
  const float* v_cache = (const float*)d_in[4];
  const int* cache_slots = (const int*)d_in[6];
  float* out = (float*)d_out;

  unsigned int* smax = (unsigned int*)d_ws;                       // 16 u32
  float* scales = (float*)((char*)d_ws + 64);                     // 16 floats
  unsigned short* k_comb = (unsigned short*)((char*)d_ws + 256);  // 8 MB
  unsigned short* v_combT = k_comb + (size_t)HKV * SKV * D;       // 8 MB

  hipMemsetAsync(smax, 0, 64, stream);
  scales_part<<<128, 256, 0, stream>>>(k, v, smax);
  scales_fin<<<1, 64, 0, stream>>>(smax, scales);
  prep_k<<<2048, 256, 0, stream>>>(k, k_cache, cache_slots, scales, k_comb);
  prep_v<<<2048, 256, 0, stream>>>(v, v_cache, cache_slots, scales, v_combT);
  attn_kernel<<<512, 256, 0, stream>>>(q, k_comb, v_combT, out);
}

// Round 7
// 133.617 us; speedup vs baseline: 3.4337x; 3.4337x over previous
//
#include <hip/hip_runtime.h>
#include <stdint.h>

#define H 32
#define HKV 8
#define D 128
#define SQ 1024
#define CTX 3072
#define SKV 4096
#define FP8_MAX_C 448.0f
#define EPS_C 1e-8f

typedef __attribute__((ext_vector_type(4))) float f32x4;
typedef __attribute__((ext_vector_type(8))) __bf16 bf16x8;
typedef __attribute__((ext_vector_type(8))) unsigned short u16x8;
typedef __attribute__((ext_vector_type(4))) unsigned short u16x4;

__device__ __forceinline__ unsigned short f2bf(float x) {
  unsigned int u = __builtin_bit_cast(unsigned int, x);
  u += 0x7fffu + ((u >> 16) & 1u);
  return (unsigned short)(u >> 16);
}

__device__ __forceinline__ f32x4 mfma16(bf16x8 a, bf16x8 b, f32x4 c) {
  return __builtin_amdgcn_mfma_f32_16x16x32_bf16(a, b, c, 0, 0, 0);
}

// async global->LDS, 16B per lane; dest = wave-uniform base + lane*16
__device__ __forceinline__ void gld16(const unsigned short* g, char* l) {
  __builtin_amdgcn_global_load_lds(
      (const __attribute__((address_space(1))) unsigned int*)g,
      (__attribute__((address_space(3))) unsigned int*)l, 16, 0, 0);
}

// Drain the global_load_lds DMA queue explicitly, then barrier.
// __syncthreads alone may not be modeled as needing vmcnt(0) for the
// LDS-write side effect of global_load_lds (replay-only race, R6).
__device__ __forceinline__ void stage_sync() {
  asm volatile("s_waitcnt vmcnt(0)" ::: "memory");
  __builtin_amdgcn_sched_barrier(0);
  __syncthreads();
}

// ---- scales stage 1: partial absmax -> atomicMax on float bits ----
__global__ void scales_part(const float* __restrict__ k,
                            const float* __restrict__ v,
                            unsigned int* __restrict__ smax) {
  const int b = blockIdx.x & 15;
  const int part = blockIdx.x >> 4;
  const float* src = (b < HKV) ? k : v;
  const int h = b & 7;
  const int tid = threadIdx.x;
  const int d0 = (tid & 31) * 4;
  float mx = 0.f;
  const int t1 = part * 128 + 128;
  for (int t = part * 128 + (tid >> 5); t < t1; t += 8) {
    float4 vv = *reinterpret_cast<const float4*>(src + (size_t)t * (HKV * D) + h * D + d0);
    mx = fmaxf(mx, fmaxf(fmaxf(fabsf(vv.x), fabsf(vv.y)),
                         fmaxf(fabsf(vv.z), fabsf(vv.w))));
  }
  __shared__ float red[256];
  red[tid] = mx;
  __syncthreads();
  for (int s = 128; s > 0; s >>= 1) {
    if (tid < s) red[tid] = fmaxf(red[tid], red[tid + s]);
    __syncthreads();
  }
  if (tid == 0) atomicMax(&smax[b], __float_as_uint(red[0]));
}

__global__ void scales_fin(const unsigned int* __restrict__ smax,
                           float* __restrict__ scales) {
  const int i = threadIdx.x;
  if (i < 16) scales[i] = fmaxf(__uint_as_float(smax[i]) / FP8_MAX_C, EPS_C);
}

// ---- prep k_comb[h][t][d] bf16 ----
__global__ void prep_k(const float* __restrict__ k,
                       const float* __restrict__ k_cache,
                       const int* __restrict__ cache_slots,
                       const float* __restrict__ scales,
                       unsigned short* __restrict__ k_comb) {
  const int tid = blockIdx.x * 256 + threadIdx.x;
  const int d8 = tid & 15;
  const int t = (tid >> 4) & (SKV - 1);
  const int h = tid >> 16;
  const int d0 = d8 * 8;
  const float* src;
  float mul;
  if (t < CTX) {
    int slot = cache_slots[t];
    src = k_cache + (size_t)slot * (HKV * D) + h * D + d0;
    mul = scales[h];
  } else {
    src = k + (size_t)(t - CTX) * (HKV * D) + h * D + d0;
    mul = 1.f;
  }
  float4 a = *reinterpret_cast<const float4*>(src);
  float4 bb = *reinterpret_cast<const float4*>(src + 4);
  u16x8 r;
  r[0] = f2bf(a.x * mul);  r[1] = f2bf(a.y * mul);
  r[2] = f2bf(a.z * mul);  r[3] = f2bf(a.w * mul);
  r[4] = f2bf(bb.x * mul); r[5] = f2bf(bb.y * mul);
  r[6] = f2bf(bb.z * mul); r[7] = f2bf(bb.w * mul);
  *reinterpret_cast<u16x8*>(k_comb + ((size_t)h * SKV + t) * D + d0) = r;
}

// ---- prep v_combT[h][d][t] bf16 ----
__global__ void prep_v(const float* __restrict__ v,
                       const float* __restrict__ v_cache,
                       const int* __restrict__ cache_slots,
                       const float* __restrict__ scales,
                       unsigned short* __restrict__ v_combT) {
  const int tid = blockIdx.x * 256 + threadIdx.x;
  const int d = tid & 127;
  const int t8 = (tid >> 7) & 511;
  const int h = tid >> 16;
  const int t0 = t8 * 8;
  const float sc = scales[8 + h];
  u16x8 r;
#pragma unroll
  for (int i = 0; i < 8; ++i) {
    int t = t0 + i;
    float val;
    if (t < CTX) {
      int slot = cache_slots[t];
      val = v_cache[(size_t)slot * (HKV * D) + h * D + d] * sc;
    } else {
      val = v[(size_t)(t - CTX) * (HKV * D) + h * D + d];
    }
    r[i] = f2bf(val);
  }
  *reinterpret_cast<u16x8*>(v_combT + ((size_t)h * D + d) * SKV + t0) = r;
}

#define LDBF(p) (*reinterpret_cast<const bf16x8*>(p))
#define Z4 ((f32x4){0.f, 0.f, 0.f, 0.f})

// Stage one 64x128 K tile (16KB) + one 128x64 V^T tile (16KB) into LDS.
// LDS dest linear; global src pre-swizzled so XOR'd ds_read is conflict-free.
#define STAGE(TB, BUFO)                                                        \
  {                                                                            \
    _Pragma("unroll")                                                          \
    for (int j = 0; j < 4; ++j) {                                              \
      const int c = wid * 256 + j * 64 + l;                                    \
      const int r_ = c >> 4;                                                   \
      const int lc_ = (c & 15) ^ (r_ & 7);                                     \
      gld16(kb + (size_t)((TB) + r_) * D + lc_ * 8,                            \
            smem + (BUFO) + (wid * 256 + j * 64) * 16);                        \
      const int dv_ = c >> 3;                                                  \
      const int lv_ = (c & 7) ^ (dv_ & 7);                                     \
      gld16(vb + (size_t)dv_ * SKV + (TB) + lv_ * 8,                           \
            smem + (BUFO) + 16384 + (wid * 256 + j * 64) * 16);                \
    }                                                                          \
  }

// exp2 + pack one s-register
#define PK(SREG, PKREG)                                                        \
  {                                                                            \
    float p0_ = __builtin_amdgcn_exp2f(SREG[0] - m);                           \
    float p1_ = __builtin_amdgcn_exp2f(SREG[1] - m);                           \
    float p2_ = __builtin_amdgcn_exp2f(SREG[2] - m);                           \
    float p3_ = __builtin_amdgcn_exp2f(SREG[3] - m);                           \
    rs += (p0_ + p1_) + (p2_ + p3_);                                           \
    PKREG[0] = f2bf(p0_); PKREG[1] = f2bf(p1_);                                \
    PKREG[2] = f2bf(p2_); PKREG[3] = f2bf(p3_);                                \
  }

// ---- flash attention: LDS-staged K/V (global_load_lds), swapped QK^T ----
__launch_bounds__(256, 2)
__global__ void attn_kernel(const float* __restrict__ q,
                            const unsigned short* __restrict__ k_comb,
                            const unsigned short* __restrict__ v_combT,
                            float* __restrict__ out) {
  extern __shared__ __align__(16) char smem[];
  // [2] x { K tile 16KB | V tile 16KB }  then p_lds (4*16*72*2 = 9216 B)
  const int bid = blockIdx.x;
  const int hkv = bid & 7;   // XCD-aware: one kv-head per XCD
  const int qt = bid >> 3;   // 0..63
  const int wid = threadIdx.x >> 6;
  const int l = threadIdx.x & 63;
  const int lo = l & 15;
  const int g = l >> 4;
  const int hq = hkv * 4 + wid;
  const int qbase = qt * 16;
  const int nt32 = 97 + (qt >> 1);
  const int n64 = (nt32 + 1) >> 1;
  const bool odd = (nt32 & 1) != 0;

  const unsigned short* kb = k_comb + (size_t)hkv * SKV * D;
  const unsigned short* vb = v_combT + (size_t)hkv * D * SKV;

  // Q fragments (B-operand), pre-scaled by SCALE*log2(e)
  bf16x8 qf0, qf1, qf2, qf3;
  {
    const float qs = 0.088388347648318447f * 1.4426950408889634f;
    const float* qp = q + (size_t)(qbase + lo) * (H * D) + hq * D;
#define QLOAD(KS, DST)                                                         \
    {                                                                          \
      float4 a = *reinterpret_cast<const float4*>(qp + KS * 32 + g * 8);       \
      float4 b = *reinterpret_cast<const float4*>(qp + KS * 32 + g * 8 + 4);   \
      union { unsigned short u[8]; bf16x8 v; } f;                              \
      f.u[0] = f2bf(a.x * qs); f.u[1] = f2bf(a.y * qs);                        \
      f.u[2] = f2bf(a.z * qs); f.u[3] = f2bf(a.w * qs);                        \
      f.u[4] = f2bf(b.x * qs); f.u[5] = f2bf(b.y * qs);                        \
      f.u[6] = f2bf(b.z * qs); f.u[7] = f2bf(b.w * qs);                        \
      DST = f.v;                                                               \
    }
    QLOAD(0, qf0) QLOAD(1, qf1) QLOAD(2, qf2) QLOAD(3, qf3)
#undef QLOAD
  }

  f32x4 acc0 = Z4, acc1 = Z4, acc2 = Z4, acc3 = Z4;
  f32x4 acc4 = Z4, acc5 = Z4, acc6 = Z4, acc7 = Z4;
  float m = -1e30f;
  float lsum = 0.f;

  // per-lane swizzled read offsets (XOR matches staged source permutation)
  const int xr = lo & 7;
  const int kx0 = ((0 + g) ^ xr) << 4;
  const int kx1 = ((4 + g) ^ xr) << 4;
  const int kx2 = ((8 + g) ^ xr) << 4;
  const int kx3 = ((12 + g) ^ xr) << 4;
  const int vxa = ((g) ^ xr) << 4;
  const int vxb = ((g + 4) ^ xr) << 4;
  const char* kbl = smem + lo * 256;           // + buf*32768 + sf*4096 + kx
  const char* vbl = smem + 16384 + lo * 128;   // + buf*32768 + dt*2048 + vx
  unsigned short* p_lds = (unsigned short*)(smem + 65536);
  unsigned short* prow = p_lds + (wid * 16 + lo) * 72;

  int cur = 0;
  STAGE(0, 0)
  stage_sync();

  for (int t = 0; t < n64; ++t) {
    const int tb = t * 64;
    if (t + 1 < n64) STAGE(tb + 64, (cur ^ 1) * 32768)

    const char* kc = kbl + cur * 32768;
    const char* vc = vbl + cur * 32768;

    // ---- K frags from LDS + swapped QK^T ----
    f32x4 s0 = Z4, s1 = Z4, s2 = Z4, s3 = Z4;
    {
      bf16x8 a0 = LDBF(kc + 0 * 4096 + kx0);
      bf16x8 a1 = LDBF(kc + 0 * 4096 + kx1);
      bf16x8 a2 = LDBF(kc + 0 * 4096 + kx2);
      bf16x8 a3 = LDBF(kc + 0 * 4096 + kx3);
      s0 = mfma16(a0, qf0, s0); s0 = mfma16(a1, qf1, s0);
      s0 = mfma16(a2, qf2, s0); s0 = mfma16(a3, qf3, s0);
    }
    {
      bf16x8 a0 = LDBF(kc + 1 * 4096 + kx0);
      bf16x8 a1 = LDBF(kc + 1 * 4096 + kx1);
      bf16x8 a2 = LDBF(kc + 1 * 4096 + kx2);
      bf16x8 a3 = LDBF(kc + 1 * 4096 + kx3);
      s1 = mfma16(a0, qf0, s1); s1 = mfma16(a1, qf1, s1);
      s1 = mfma16(a2, qf2, s1); s1 = mfma16(a3, qf3, s1);
    }
    {
      bf16x8 a0 = LDBF(kc + 2 * 4096 + kx0);
      bf16x8 a1 = LDBF(kc + 2 * 4096 + kx1);
      bf16x8 a2 = LDBF(kc + 2 * 4096 + kx2);
      bf16x8 a3 = LDBF(kc + 2 * 4096 + kx3);
      s2 = mfma16(a0, qf0, s2); s2 = mfma16(a1, qf1, s2);
      s2 = mfma16(a2, qf2, s2); s2 = mfma16(a3, qf3, s2);
    }
    {
      bf16x8 a0 = LDBF(kc + 3 * 4096 + kx0);
      bf16x8 a1 = LDBF(kc + 3 * 4096 + kx1);
      bf16x8 a2 = LDBF(kc + 3 * 4096 + kx2);
      bf16x8 a3 = LDBF(kc + 3 * 4096 + kx3);
      s3 = mfma16(a0, qf0, s3); s3 = mfma16(a1, qf1, s3);
      s3 = mfma16(a2, qf2, s3); s3 = mfma16(a3, qf3, s3);
    }

    // ---- mask invalid upper half of odd-count last tile ----
    if (odd && t == n64 - 1) {
      s2 = (f32x4){-1e30f, -1e30f, -1e30f, -1e30f};
      s3 = (f32x4){-1e30f, -1e30f, -1e30f, -1e30f};
    }

    // ---- lazy online softmax (no cross-lane in common path) ----
    float pmax = fmaxf(fmaxf(fmaxf(s0[0], s0[1]), fmaxf(s0[2], s0[3])),
                       fmaxf(fmaxf(s1[0], s1[1]), fmaxf(s1[2], s1[3])));
    pmax = fmaxf(pmax,
                 fmaxf(fmaxf(fmaxf(s2[0], s2[1]), fmaxf(s2[2], s2[3])),
                       fmaxf(fmaxf(s3[0], s3[1]), fmaxf(s3[2], s3[3]))));
    if (!__all(pmax - m <= 8.f)) {
      float rm = fmaxf(pmax, __shfl_xor(pmax, 16));
      rm = fmaxf(rm, __shfl_xor(rm, 32));
      float mn = fmaxf(m, rm);
      float scl = __builtin_amdgcn_exp2f(m - mn);
      lsum *= scl;
      acc0 *= scl; acc1 *= scl; acc2 *= scl; acc3 *= scl;
      acc4 *= scl; acc5 *= scl; acc6 *= scl; acc7 *= scl;
      m = mn;
    }

    float rs = 0.f;
    u16x4 pk0, pk1, pk2, pk3;
    PK(s0, pk0) PK(s1, pk1) PK(s2, pk2) PK(s3, pk3)
    lsum += rs;

    // ---- P transpose through per-wave LDS (no barrier) ----
    *reinterpret_cast<u16x4*>(prow + 0 * 16 + g * 4) = pk0;
    *reinterpret_cast<u16x4*>(prow + 1 * 16 + g * 4) = pk1;
    *reinterpret_cast<u16x4*>(prow + 2 * 16 + g * 4) = pk2;
    *reinterpret_cast<u16x4*>(prow + 3 * 16 + g * 4) = pk3;
    bf16x8 pf0 = LDBF(prow + g * 8);
    bf16x8 pf1 = LDBF(prow + 32 + g * 8);

    // ---- V frags from LDS + PV ----
    {
      bf16x8 va = LDBF(vc + 0 * 2048 + vxa), vb_ = LDBF(vc + 0 * 2048 + vxb);
      acc0 = mfma16(pf0, va, acc0); acc0 = mfma16(pf1, vb_, acc0);
    }
    {
      bf16x8 va = LDBF(vc + 1 * 2048 + vxa), vb_ = LDBF(vc + 1 * 2048 + vxb);
      acc1 = mfma16(pf0, va, acc1); acc1 = mfma16(pf1, vb_, acc1);
    }
    {
      bf16x8 va = LDBF(vc + 2 * 2048 + vxa), vb_ = LDBF(vc + 2 * 2048 + vxb);
      acc2 = mfma16(pf0, va, acc2); acc2 = mfma16(pf1, vb_, acc2);
    }
    {
      bf16x8 va = LDBF(vc + 3 * 2048 + vxa), vb_ = LDBF(vc + 3 * 2048 + vxb);
      acc3 = mfma16(pf0, va, acc3); acc3 = mfma16(pf1, vb_, acc3);
    }
    {
      bf16x8 va = LDBF(vc + 4 * 2048 + vxa), vb_ = LDBF(vc + 4 * 2048 + vxb);
      acc4 = mfma16(pf0, va, acc4); acc4 = mfma16(pf1, vb_, acc4);
    }
    {
      bf16x8 va = LDBF(vc + 5 * 2048 + vxa), vb_ = LDBF(vc + 5 * 2048 + vxb);
      acc5 = mfma16(pf0, va, acc5); acc5 = mfma16(pf1, vb_, acc5);
    }
    {
      bf16x8 va = LDBF(vc + 6 * 2048 + vxa), vb_ = LDBF(vc + 6 * 2048 + vxb);
      acc6 = mfma16(pf0, va, acc6); acc6 = mfma16(pf1, vb_, acc6);
    }
    {
      bf16x8 va = LDBF(vc + 7 * 2048 + vxa), vb_ = LDBF(vc + 7 * 2048 + vxb);
      acc7 = mfma16(pf0, va, acc7); acc7 = mfma16(pf1, vb_, acc7);
    }

    stage_sync();  // explicit vmcnt(0) drain + barrier
    cur ^= 1;
  }

  // ---- epilogue: reduce denom, broadcast to C-layout rows, store ----
  lsum += __shfl_xor(lsum, 16);
  lsum += __shfl_xor(lsum, 32);
#pragma unroll
  for (int r = 0; r < 4; ++r) {
    int src = (l & 48) | (g * 4 + r);
    float inv = 1.f / __shfl(lsum, src);
    float* op = out + (size_t)(qbase + g * 4 + r) * (H * D) + hq * D + lo;
    op[0 * 16] = acc0[r] * inv;
    op[1 * 16] = acc1[r] * inv;
    op[2 * 16] = acc2[r] * inv;
    op[3 * 16] = acc3[r] * inv;
    op[4 * 16] = acc4[r] * inv;
    op[5 * 16] = acc5[r] * inv;
    op[6 * 16] = acc6[r] * inv;
    op[7 * 16] = acc7[r] * inv;
  }
}

extern "C" void kernel_launch(void* const* d_in, const int* in_sizes, int n_in,
                              void* d_out, int out_size, void* d_ws, size_t ws_size,
                              hipStream_t stream) {
  (void)in_sizes; (void)n_in; (void)out_size; (void)ws_size;
  const float* q = (const float*)d_in[0];
  const float* k = (const float*)d_in[1];
  const float* v = (const float*)d_in[2];
  const float* k_cache = (const float*)d_in[3];
  const float* v_cache = (const float*)d_in[4];
  const int* cache_slots = (const int*)d_in[6];
  float* out = (float*)d_out;

  unsigned int* smax = (unsigned int*)d_ws;                       // 16 u32
  float* scales = (float*)((char*)d_ws + 64);                     // 16 floats
  unsigned short* k_comb = (unsigned short*)((char*)d_ws + 256);  // 8 MB
  unsigned short* v_combT = k_comb + (size_t)HKV * SKV * D;       // 8 MB

  hipMemsetAsync(smax, 0, 64, stream);
  scales_part<<<128, 256, 0, stream>>>(k, v, smax);
  scales_fin<<<1, 64, 0, stream>>>(smax, scales);
  prep_k<<<2048, 256, 0, stream>>>(k, k_cache, cache_slots, scales, k_comb);
  prep_v<<<2048, 256, 0, stream>>>(v, v_cache, cache_slots, scales, v_combT);
  attn_kernel<<<512, 256, 74752, stream>>>(q, k_comb, v_combT, out);
}